// Round 1
// baseline (4357.376 us; speedup 1.0000x reference)
//
#include <hip/hip_runtime.h>
#include <hip/hip_bf16.h>

typedef _Float16 half2v __attribute__((ext_vector_type(2)));
typedef _Float16 half8v __attribute__((ext_vector_type(8)));
typedef float float4v __attribute__((ext_vector_type(4)));
typedef unsigned int u32;

#define DEV static __device__ __forceinline__

DEV u32 pack2(float a, float b) {
  half2v h = { (_Float16)a, (_Float16)b };
  return __builtin_bit_cast(u32, h);
}
DEV half2v uph(u32 u) { return __builtin_bit_cast(half2v, u); }

#if __has_builtin(__builtin_amdgcn_fdot2)
DEV float fdot2(half2v a, half2v b, float c) { return __builtin_amdgcn_fdot2(a, b, c, false); }
#else
DEV float fdot2(half2v a, half2v b, float c) {
  return c + (float)a.x * (float)b.x + (float)a.y * (float)b.y;
}
#endif

DEV float fast_rcp(float x) { return __builtin_amdgcn_rcpf(x); }
DEV float sigmoid_f(float x) { return fast_rcp(1.f + exp2f(-1.4426950408889634f * x)); }
DEV float tanh_f(float x) {
  float e = exp2f(x * 2.8853900817779268f);  // e^(2x)
  return 1.f - 2.f * fast_rcp(e + 1.f);
}

// ---------------------------------------------------------------------------
// Prep: transpose + f16-convert the three weight matrices (dst[c][r] = src[r][c])
// ---------------------------------------------------------------------------
__global__ void prep_transpose(const float* __restrict__ Wz, const float* __restrict__ Wh,
                               const float* __restrict__ Wo, _Float16* __restrict__ Wzt,
                               _Float16* __restrict__ Wht, _Float16* __restrict__ Wot)
{
  const float* src; _Float16* dst; int R, C;
  if (blockIdx.y == 0)      { src = Wz; dst = Wzt; R = 128; C = 256; }
  else if (blockIdx.y == 1) { src = Wh; dst = Wht; R = 128; C = 256; }
  else                      { src = Wo; dst = Wot; R = 256; C = 128; }
  int total = R * C;
  for (int idx = blockIdx.x * blockDim.x + threadIdx.x; idx < total;
       idx += gridDim.x * blockDim.x) {
    int rr = idx / C, cc = idx % C;
    dst[(size_t)cc * R + rr] = (_Float16)src[idx];
  }
}

// ---------------------------------------------------------------------------
// MFMA GEMM: out[M x N] = A[M x K] * Bt^T (+bias). Bt is [N][K] f16 (pre-transposed).
// M-tile 128/WG, 4 waves, wave w owns m-subtiles {2w, 2w+1}. B staged in LDS with
// XOR-chunk swizzle (64 KB exactly, no padding, conflict-free b128 frag reads).
// ---------------------------------------------------------------------------
template <int K, int N, bool A_F32, bool OUT_F16>
__global__ __launch_bounds__(256, 2) void gemm_mfma(
    const void* __restrict__ A_, const _Float16* __restrict__ Bt,
    const float* __restrict__ bias, void* __restrict__ out)
{
  __shared__ _Float16 Blds[N * K];  // 64 KB

  const int tid = threadIdx.x;
  constexpr int CHUNKS = K / 8;          // 16B chunks per row
  constexpr int ITER = (N * K / 8) / 256;
#pragma unroll
  for (int i = 0; i < ITER; ++i) {
    int idx = tid + i * 256;
    int n = idx / CHUNKS;
    int c = idx % CHUNKS;
    int cs = c ^ (n & 7);               // XOR swizzle on 16B-chunk position
    *(uint4*)(Blds + (size_t)n * K + cs * 8) =
        *(const uint4*)(Bt + (size_t)n * K + c * 8);
  }
  __syncthreads();

  const int w = tid >> 6, l = tid & 63;
  const int lm = l & 15, lq = l >> 4;
  const size_t m0 = (size_t)blockIdx.x * 128;

  float4v acc[2][N / 16] = {};

#pragma unroll
  for (int kk = 0; kk < K / 32; ++kk) {
    const int kbase = kk * 32 + lq * 8;
    half8v af[2];
#pragma unroll
    for (int ms = 0; ms < 2; ++ms) {
      const size_t row = m0 + (size_t)(w * 2 + ms) * 16 + lm;
      if constexpr (A_F32) {
        const float* ap = (const float*)A_ + row * K + kbase;
        float4 x0 = *(const float4*)ap;
        float4 x1 = *(const float4*)(ap + 4);
        af[ms] = half8v{(_Float16)x0.x, (_Float16)x0.y, (_Float16)x0.z, (_Float16)x0.w,
                        (_Float16)x1.x, (_Float16)x1.y, (_Float16)x1.z, (_Float16)x1.w};
      } else {
        af[ms] = *(const half8v*)((const _Float16*)A_ + row * K + kbase);
      }
    }
    const int c = kk * 4 + lq;          // 16B chunk index of this frag
#pragma unroll
    for (int nt = 0; nt < N / 16; ++nt) {
      const int n = nt * 16 + lm;
      half8v bf = *(const half8v*)(Blds + (size_t)n * K + (c ^ (lm & 7)) * 8);
      acc[0][nt] = __builtin_amdgcn_mfma_f32_16x16x32_f16(af[0], bf, acc[0][nt], 0, 0, 0);
      acc[1][nt] = __builtin_amdgcn_mfma_f32_16x16x32_f16(af[1], bf, acc[1][nt], 0, 0, 0);
    }
  }

  // epilogue: C layout col = lane&15, row = (lane>>4)*4 + reg
#pragma unroll
  for (int ms = 0; ms < 2; ++ms) {
    const size_t rowbase = m0 + (size_t)(w * 2 + ms) * 16 + lq * 4;
#pragma unroll
    for (int nt = 0; nt < N / 16; ++nt) {
      const int col = nt * 16 + lm;
      const float bcol = bias[col];
#pragma unroll
      for (int rr = 0; rr < 4; ++rr) {
        const size_t row = rowbase + rr;
        float v = acc[ms][nt][rr] + bcol;
        if constexpr (OUT_F16) ((_Float16*)out)[row * N + col] = (_Float16)v;
        else                   ((float*)out)[row * N + col] = v;
      }
    }
  }
}

// ---------------------------------------------------------------------------
// Sequential scan. One WG (512 thr, 8 waves) per batch element.
// waves 0-3 (g=0): candidate gate, Uh in regs;  waves 4-7 (g=1): z gate, Uz in regs.
// Lane mapping: P = (w&3)*32 + (l&31) -> columns 2P,2P+1 ; r = l>>5 -> K half.
// Per step: LDS-broadcast a-vector read, 128 v_dot2, shfl_xor(32) reduce,
// activation + state update on lanes<32, ONE barrier.
// z_{t+1} computed at step t from h_{t-4} (delay line), ping-pong LDS buffer.
// ---------------------------------------------------------------------------
__global__ __launch_bounds__(512, 2) void scan_kernel(
    const u32* __restrict__ xz32, const u32* __restrict__ xh32,
    const float* __restrict__ Uz, const float* __restrict__ Uh,
    u32* __restrict__ hsOut)
{
  const int b   = blockIdx.x;
  const int tid = threadIdx.x;
  const int w   = tid >> 6;
  const int l   = tid & 63;
  const int g   = w >> 2;            // 0: candidate (Uh), 1: gate (Uz)
  const int P   = (w & 3) * 32 + (l & 31);
  const int r   = l >> 5;
  const int c0  = 2 * P;

  __shared__ u32 histS[8][128];      // h history, f16 pairs
  __shared__ u32 zbufS[2][128];      // z ping-pong, f16 pairs

  // ---- U -> registers: packed f16 row-pairs of columns c0, c0+1, K-half r ----
  const float* U = g ? Uz : Uh;
  u32 uA[64], uB[64];
  {
    const float* Ub = U + (size_t)(128 * r) * 256 + c0;
#pragma unroll
    for (int i = 0; i < 64; ++i) {
      float2 va = *(const float2*)(Ub + (size_t)(2 * i) * 256);
      float2 vb = *(const float2*)(Ub + (size_t)(2 * i + 1) * 256);
      uA[i] = pack2(va.x, vb.x);     // column c0, rows 2i,2i+1
      uB[i] = pack2(va.y, vb.y);     // column c0+1
    }
  }

  // zero history slots 4..7 (h_{-4..-1})
  histS[4 + (tid >> 7)][tid & 127] = 0;

  const u32* xv = g ? xz32 : xh32;
  const size_t xbase = (size_t)b * 4096 * 128;

  u32 xpre[4];
  if (l < 32) {
#pragma unroll
    for (int i = 0; i < 4; ++i) {
      int tt = g ? (i + 1) : i;      // g0 holds xh[t], g1 holds xz[t+1]
      xpre[i] = xv[xbase + (size_t)tt * 128 + P];
    }
    if (g) {                         // z_0 = sigmoid(xz_0)  (h_{-5} = 0)
      half2v x0 = uph(xv[xbase + P]);
      zbufS[0][P] = pack2(sigmoid_f((float)x0.x), sigmoid_f((float)x0.y));
    }
  }
  float h0 = 0.f, h1 = 0.f;
  __syncthreads();

  for (int tb = 0; tb < 4096; tb += 8) {
#pragma unroll
    for (int u = 0; u < 8; ++u) {
      const int t = tb + u;
      // a-vector source: g0 -> h_{t-1} (times z_t), g1 -> h_{t-4}
      const u32* arow = g ? &histS[(u + 4) & 7][r * 64]
                          : &histS[(u + 7) & 7][r * 64];
      const u32* zrow = &zbufS[u & 1][r * 64];

      float s0[4] = {0.f, 0.f, 0.f, 0.f};
      float s1[4] = {0.f, 0.f, 0.f, 0.f};
#pragma unroll
      for (int i = 0; i < 64; i += 16) {
        const uint4* a4 = (const uint4*)(arow + i);
        uint4 A0 = a4[0], A1 = a4[1], A2 = a4[2], A3 = a4[3];
        u32 av[16];
        av[0]=A0.x; av[1]=A0.y; av[2]=A0.z; av[3]=A0.w;
        av[4]=A1.x; av[5]=A1.y; av[6]=A1.z; av[7]=A1.w;
        av[8]=A2.x; av[9]=A2.y; av[10]=A2.z; av[11]=A2.w;
        av[12]=A3.x; av[13]=A3.y; av[14]=A3.z; av[15]=A3.w;
        if (!g) {                     // a = z_t (.) h_{t-1}
          const uint4* z4 = (const uint4*)(zrow + i);
          uint4 Z0 = z4[0], Z1 = z4[1], Z2 = z4[2], Z3 = z4[3];
          u32 zv[16];
          zv[0]=Z0.x; zv[1]=Z0.y; zv[2]=Z0.z; zv[3]=Z0.w;
          zv[4]=Z1.x; zv[5]=Z1.y; zv[6]=Z1.z; zv[7]=Z1.w;
          zv[8]=Z2.x; zv[9]=Z2.y; zv[10]=Z2.z; zv[11]=Z2.w;
          zv[12]=Z3.x; zv[13]=Z3.y; zv[14]=Z3.z; zv[15]=Z3.w;
#pragma unroll
          for (int j = 0; j < 16; ++j)
            av[j] = __builtin_bit_cast(u32, uph(av[j]) * uph(zv[j]));
        }
#pragma unroll
        for (int j = 0; j < 16; ++j) {
          half2v a2 = uph(av[j]);
          s0[j & 3] = fdot2(a2, uph(uA[i + j]), s0[j & 3]);
          s1[j & 3] = fdot2(a2, uph(uB[i + j]), s1[j & 3]);
        }
      }
      float acc0 = (s0[0] + s0[1]) + (s0[2] + s0[3]);
      float acc1 = (s1[0] + s1[1]) + (s1[2] + s1[3]);
      acc0 += __shfl_xor(acc0, 32);
      acc1 += __shfl_xor(acc1, 32);

      if (l < 32) {
        half2v xp = uph(xpre[u & 3]);
        if (g == 0) {
          half2v zp = uph(zbufS[u & 1][P]);   // z_t for my columns
          float ht0 = tanh_f(acc0 + (float)xp.x);
          float ht1 = tanh_f(acc1 + (float)xp.y);
          float z0 = (float)zp.x, z1 = (float)zp.y;
          h0 += z0 * (ht0 - h0);              // h = (1-z)h + z*htilde
          h1 += z1 * (ht1 - h1);
          u32 hp = pack2(h0, h1);
          histS[u][P] = hp;                    // slot t&7 == u
          hsOut[xbase + (size_t)t * 128 + P] = hp;
          int tld = t + 4; if (tld > 4095) tld = 4095;
          xpre[u & 3] = xv[xbase + (size_t)tld * 128 + P];
        } else {
          float z0 = sigmoid_f(acc0 + (float)xp.x);  // z_{t+1}
          float z1 = sigmoid_f(acc1 + (float)xp.y);
          zbufS[(u + 1) & 1][P] = pack2(z0, z1);
          int tld = t + 5; if (tld > 4095) tld = 4095;
          xpre[u & 3] = xv[xbase + (size_t)tld * 128 + P];
        }
      }
      __syncthreads();
    }
  }
}

// ---------------------------------------------------------------------------
extern "C" void kernel_launch(void* const* d_in, const int* in_sizes, int n_in,
                              void* d_out, int out_size, void* d_ws, size_t ws_size,
                              hipStream_t stream)
{
  (void)in_sizes; (void)n_in; (void)out_size; (void)ws_size;
  const float* x  = (const float*)d_in[0];
  const float* Wz = (const float*)d_in[1];
  const float* Uz = (const float*)d_in[2];
  const float* bz = (const float*)d_in[3];
  const float* Wh = (const float*)d_in[4];
  const float* Uh = (const float*)d_in[5];
  const float* bh = (const float*)d_in[6];
  const float* Wo = (const float*)d_in[7];
  const float* bo = (const float*)d_in[8];

  char* ws = (char*)d_ws;
  _Float16* Wzt  = (_Float16*)(ws);                                   // 64 KB
  _Float16* Wht  = (_Float16*)(ws + (64 << 10));                      // 64 KB
  _Float16* Wot  = (_Float16*)(ws + (128 << 10));                     // 64 KB
  _Float16* xz16 = (_Float16*)(ws + (256 << 10));                     // 64 MB
  _Float16* xh16 = (_Float16*)(ws + (256 << 10) + (size_t)64 * 1024 * 1024); // 64 MB

  // hs (f16, [B][L][H]) lives inside d_out; head GEMM then overwrites d_out
  // in place (row m reads hs bytes [512m,512m+512) and writes y to the same
  // range; rows are wave/WG-disjoint, stores depend on the loads -> safe).
  _Float16* hs16 = (_Float16*)d_out;

  prep_transpose<<<dim3(32, 3), 256, 0, stream>>>(Wz, Wh, Wo, Wzt, Wht, Wot);
  gemm_mfma<128, 256, true, true><<<1024, 256, 0, stream>>>(x, Wzt, bz, xz16);
  gemm_mfma<128, 256, true, true><<<1024, 256, 0, stream>>>(x, Wht, bh, xh16);
  scan_kernel<<<32, 512, 0, stream>>>((const u32*)xz16, (const u32*)xh16,
                                      Uz, Uh, (u32*)d_out);
  gemm_mfma<256, 128, false, false><<<1024, 256, 0, stream>>>(hs16, Wot, bo, d_out);
}

// Round 2
// 3877.327 us; speedup vs baseline: 1.1238x; 1.1238x over previous
//
#include <hip/hip_runtime.h>
#include <hip/hip_bf16.h>

typedef _Float16 half2v __attribute__((ext_vector_type(2)));
typedef _Float16 half8v __attribute__((ext_vector_type(8)));
typedef float float4v __attribute__((ext_vector_type(4)));
typedef unsigned int u32;

#define DEV static __device__ __forceinline__

DEV u32 pack2(float a, float b) {
  half2v h = { (_Float16)a, (_Float16)b };
  return __builtin_bit_cast(u32, h);
}
DEV half2v uph(u32 u) { return __builtin_bit_cast(half2v, u); }
DEV u32 pmul(u32 a, u32 z) { return __builtin_bit_cast(u32, uph(a) * uph(z)); }
DEV unsigned short ftoh16(float f) { return __builtin_bit_cast(unsigned short, (_Float16)f); }
DEV float h16tof(unsigned short s) { return (float)__builtin_bit_cast(_Float16, s); }

#if __has_builtin(__builtin_amdgcn_fdot2)
DEV float fdot2(half2v a, half2v b, float c) { return __builtin_amdgcn_fdot2(a, b, c, false); }
#else
DEV float fdot2(half2v a, half2v b, float c) {
  return c + (float)a.x * (float)b.x + (float)a.y * (float)b.y;
}
#endif

DEV float fast_rcp(float x) { return __builtin_amdgcn_rcpf(x); }
DEV float sigmoid_f(float x) { return fast_rcp(1.f + exp2f(-1.4426950408889634f * x)); }
DEV float tanh_f(float x) {
  float e = exp2f(x * 2.8853900817779268f);  // e^(2x)
  return 1.f - 2.f * fast_rcp(e + 1.f);
}

// ---------------------------------------------------------------------------
// Prep: transpose + f16-convert the three weight matrices (dst[c][r] = src[r][c])
// ---------------------------------------------------------------------------
__global__ void prep_transpose(const float* __restrict__ Wz, const float* __restrict__ Wh,
                               const float* __restrict__ Wo, _Float16* __restrict__ Wzt,
                               _Float16* __restrict__ Wht, _Float16* __restrict__ Wot)
{
  const float* src; _Float16* dst; int R, C;
  if (blockIdx.y == 0)      { src = Wz; dst = Wzt; R = 128; C = 256; }
  else if (blockIdx.y == 1) { src = Wh; dst = Wht; R = 128; C = 256; }
  else                      { src = Wo; dst = Wot; R = 256; C = 128; }
  int total = R * C;
  for (int idx = blockIdx.x * blockDim.x + threadIdx.x; idx < total;
       idx += gridDim.x * blockDim.x) {
    int rr = idx / C, cc = idx % C;
    dst[(size_t)cc * R + rr] = (_Float16)src[idx];
  }
}

// ---------------------------------------------------------------------------
// MFMA GEMM: out[M x N] = A[M x K] * Bt^T (+bias). Bt is [N][K] f16 (pre-transposed).
// ---------------------------------------------------------------------------
template <int K, int N, bool A_F32, bool OUT_F16>
__global__ __launch_bounds__(256, 2) void gemm_mfma(
    const void* __restrict__ A_, const _Float16* __restrict__ Bt,
    const float* __restrict__ bias, void* __restrict__ out)
{
  __shared__ _Float16 Blds[N * K];  // 64 KB

  const int tid = threadIdx.x;
  constexpr int CHUNKS = K / 8;
  constexpr int ITER = (N * K / 8) / 256;
#pragma unroll
  for (int i = 0; i < ITER; ++i) {
    int idx = tid + i * 256;
    int n = idx / CHUNKS;
    int c = idx % CHUNKS;
    int cs = c ^ (n & 7);
    *(uint4*)(Blds + (size_t)n * K + cs * 8) =
        *(const uint4*)(Bt + (size_t)n * K + c * 8);
  }
  __syncthreads();

  const int w = tid >> 6, l = tid & 63;
  const int lm = l & 15, lq = l >> 4;
  const size_t m0 = (size_t)blockIdx.x * 128;

  float4v acc[2][N / 16] = {};

#pragma unroll
  for (int kk = 0; kk < K / 32; ++kk) {
    const int kbase = kk * 32 + lq * 8;
    half8v af[2];
#pragma unroll
    for (int ms = 0; ms < 2; ++ms) {
      const size_t row = m0 + (size_t)(w * 2 + ms) * 16 + lm;
      if constexpr (A_F32) {
        const float* ap = (const float*)A_ + row * K + kbase;
        float4 x0 = *(const float4*)ap;
        float4 x1 = *(const float4*)(ap + 4);
        af[ms] = half8v{(_Float16)x0.x, (_Float16)x0.y, (_Float16)x0.z, (_Float16)x0.w,
                        (_Float16)x1.x, (_Float16)x1.y, (_Float16)x1.z, (_Float16)x1.w};
      } else {
        af[ms] = *(const half8v*)((const _Float16*)A_ + row * K + kbase);
      }
    }
    const int c = kk * 4 + lq;
#pragma unroll
    for (int nt = 0; nt < N / 16; ++nt) {
      const int n = nt * 16 + lm;
      half8v bf = *(const half8v*)(Blds + (size_t)n * K + (c ^ (lm & 7)) * 8);
      acc[0][nt] = __builtin_amdgcn_mfma_f32_16x16x32_f16(af[0], bf, acc[0][nt], 0, 0, 0);
      acc[1][nt] = __builtin_amdgcn_mfma_f32_16x16x32_f16(af[1], bf, acc[1][nt], 0, 0, 0);
    }
  }

#pragma unroll
  for (int ms = 0; ms < 2; ++ms) {
    const size_t rowbase = m0 + (size_t)(w * 2 + ms) * 16 + lq * 4;
#pragma unroll
    for (int nt = 0; nt < N / 16; ++nt) {
      const int col = nt * 16 + lm;
      const float bcol = bias[col];
#pragma unroll
      for (int rr = 0; rr < 4; ++rr) {
        const size_t row = rowbase + rr;
        float v = acc[ms][nt][rr] + bcol;
        if constexpr (OUT_F16) ((_Float16*)out)[row * N + col] = (_Float16)v;
        else                   ((float*)out)[row * N + col] = v;
      }
    }
  }
}

// ---------------------------------------------------------------------------
// Sequential scan. One WG (512 thr, 8 waves) per batch element.
//  waves 0-3 (g=0): candidate gate, VALU dot2, Uh packed in regs (W[0..31]).
//  waves 4-7 (g=1): z gate via MFMA, Uz B-frags in regs (W[0..31] overlay);
//    exploits the 5-step delay: once per 4 steps (u==3) computes
//    z_{tb+4..tb+7} = sigmoid(xz + [h_{tb-1..tb+2}] @ Uz) as one M=4-used
//    16x16x32 MFMA burst (32 MFMA/wave).  All global traffic (xh->LDS ring,
//    xz gather, hs writeback) is issued by g1 at u==0 so the single vmcnt(0)
//    barrier drain overlaps g0's compute; g0 waves touch ONLY LDS.
// ---------------------------------------------------------------------------
__global__ __launch_bounds__(512, 2) void scan_kernel(
    const u32* __restrict__ xz32, const u32* __restrict__ xh32,
    const float* __restrict__ Uz, const float* __restrict__ Uh,
    u32* __restrict__ hsOut)
{
  const int b   = blockIdx.x;
  const int tid = threadIdx.x;
  const int w   = tid >> 6;
  const int l   = tid & 63;
  const int g   = w >> 2;
  const int wv  = w & 3;
  const int P   = wv * 32 + (l & 31);
  const int r   = l >> 5;

  // histS rows padded to 132 u32 so MFMA A-frag reads (4 consecutive slots)
  // land in different bank groups.
  __shared__ __align__(16) u32 histS[8][132];            // h ring, f16 pairs
  __shared__ __align__(16) unsigned short zringS[8][264]; // z ring, f16
  __shared__ __align__(16) u32 xringS[2][4][128];        // xh staging, f16 pairs

  uint4 W[32];  // overlay: g0 = Uh packs (uA->W[0..15], uB->W[16..31]);
                //          g1 = Uz B-frags W[kt*4+nt]

  const size_t xb32 = (size_t)b * 4096 * 128;   // u32 units
  const unsigned short* xz16v = (const unsigned short*)xz32;

  if (g == 0) {
    // --- Uh -> packed f16 pairs. W[i] comps p: columns {2P,2P+1}, rows {8i+2p,8i+2p+1}+128r
    const int c0 = 2 * P;
    const float* Ub = Uh + (size_t)(128 * r) * 256 + c0;
#pragma unroll
    for (int ii = 0; ii < 16; ++ii) {
      u32 qa[4], qb[4];
#pragma unroll
      for (int p = 0; p < 4; ++p) {
        int i = ii * 4 + p;
        float2 va = *(const float2*)(Ub + (size_t)(2 * i) * 256);
        float2 vb = *(const float2*)(Ub + (size_t)(2 * i + 1) * 256);
        qa[p] = pack2(va.x, vb.x);
        qb[p] = pack2(va.y, vb.y);
      }
      W[ii]      = make_uint4(qa[0], qa[1], qa[2], qa[3]);
      W[16 + ii] = make_uint4(qb[0], qb[1], qb[2], qb[3]);
    }
  } else {
    // --- Uz -> B-fragments: W[kt*4+nt] = B[k = kt*32+(l>>4)*8+j][n = wv*64+nt*16+(l&15)]
    const int lm = l & 15, lo = (l >> 4) * 8;
#pragma unroll
    for (int kt = 0; kt < 8; ++kt)
#pragma unroll
      for (int nt = 0; nt < 4; ++nt) {
        u32 q[4];
#pragma unroll
        for (int p = 0; p < 4; ++p) {
          int k0 = kt * 32 + lo + 2 * p;
          int cc = wv * 64 + nt * 16 + lm;
          float v0 = Uz[(size_t)k0 * 256 + cc];
          float v1 = Uz[(size_t)(k0 + 1) * 256 + cc];
          q[p] = pack2(v0, v1);
        }
        W[kt * 4 + nt] = make_uint4(q[0], q[1], q[2], q[3]);
      }
  }

  // zero h_{-4..-1} (slots 4..7, incl. pad)
  for (int i = tid; i < 4 * 132; i += 512) (&histS[4][0])[i] = 0;

  if (g == 1) {
    // z_0..z_3 = sigmoid(xz_t)  (h_{t-5} = 0)
    const int c = (w - 4) * 64 + l;
#pragma unroll
    for (int rr = 0; rr < 4; ++rr)
      zringS[rr][c] = ftoh16(sigmoid_f(h16tof(xz16v[((size_t)b * 4096 + rr) * 256 + c])));
    // xh rows 0..3 -> xringS[0]
    const int idx = (w - 4) * 64 + l;
    const int rr = idx >> 6, cc = (idx & 63) * 2;
    *(uint2*)&xringS[0][rr][cc] = *(const uint2*)&xh32[xb32 + (size_t)rr * 128 + cc];
  }

  float h0 = 0.f, h1 = 0.f;
  unsigned short xq[4][4];
  __syncthreads();

  for (int tb = 0; tb < 4096; tb += 4) {
#pragma unroll
    for (int u = 0; u < 4; ++u) {
      const int t = tb + u;
      if (g == 0) {
        // ---------------- candidate gate: h_t ----------------
        const uint4* a4 = (const uint4*)&histS[(t + 7) & 7][r * 64];     // h_{t-1}
        const uint4* z4 = (const uint4*)&zringS[t & 7][r * 128];         // z_t
        // early-issue the leader operands (consumed after the reduce)
        u32 xp32 = xringS[(tb >> 2) & 1][u][P];
        u32 zp32 = *(const u32*)((const unsigned short*)zringS[t & 7] + 2 * P);

        float s0[4] = {0.f, 0.f, 0.f, 0.f};
        float s1[4] = {0.f, 0.f, 0.f, 0.f};
#pragma unroll
        for (int i = 0; i < 16; ++i) {
          uint4 A = a4[i], Z = z4[i];
          uint4 Wa = W[i], Wb = W[16 + i];
          u32 p0 = pmul(A.x, Z.x), p1 = pmul(A.y, Z.y);
          u32 p2 = pmul(A.z, Z.z), p3 = pmul(A.w, Z.w);
          s0[0] = fdot2(uph(p0), uph(Wa.x), s0[0]); s1[0] = fdot2(uph(p0), uph(Wb.x), s1[0]);
          s0[1] = fdot2(uph(p1), uph(Wa.y), s0[1]); s1[1] = fdot2(uph(p1), uph(Wb.y), s1[1]);
          s0[2] = fdot2(uph(p2), uph(Wa.z), s0[2]); s1[2] = fdot2(uph(p2), uph(Wb.z), s1[2]);
          s0[3] = fdot2(uph(p3), uph(Wa.w), s0[3]); s1[3] = fdot2(uph(p3), uph(Wb.w), s1[3]);
        }
        float acc0 = (s0[0] + s0[1]) + (s0[2] + s0[3]);
        float acc1 = (s1[0] + s1[1]) + (s1[2] + s1[3]);
        acc0 += __shfl_xor(acc0, 32);
        acc1 += __shfl_xor(acc1, 32);

        if (l < 32) {
          half2v xp = uph(xp32), zp = uph(zp32);
          float ht0 = tanh_f(acc0 + (float)xp.x);
          float ht1 = tanh_f(acc1 + (float)xp.y);
          h0 += (float)zp.x * (ht0 - h0);
          h1 += (float)zp.y * (ht1 - h1);
          histS[t & 7][P] = pack2(h0, h1);
        }
      } else {
        // ---------------- z gate (4-step slack) ----------------
        const int idx = (w - 4) * 64 + l;
        if (u == 0) {
          // ALL global traffic here: one vmcnt drain per 4 steps, hidden
          // under g0's compute.
          const int rr = idx >> 6, cc = (idx & 63) * 2;
          int row = tb + 4 + rr; if (row > 4095) row = 4095;
          uint2 xv = *(const uint2*)&xh32[xb32 + (size_t)row * 128 + cc];
          *(uint2*)&xringS[((tb >> 2) + 1) & 1][rr][cc] = xv;
          if (l < 16) {
#pragma unroll
            for (int nt = 0; nt < 4; ++nt)
#pragma unroll
              for (int rr2 = 0; rr2 < 4; ++rr2) {
                int rz = tb + 4 + rr2; if (rz > 4095) rz = 4095;
                xq[nt][rr2] = xz16v[((size_t)b * 4096 + rz) * 256 + wv * 64 + nt * 16 + l];
              }
          }
          if (tb > 0) {  // write back h rows tb-4..tb-1
            const int row2 = tb - 4 + rr;
            uint2 hv = *(const uint2*)&histS[row2 & 7][cc];
            *(uint2*)&hsOut[xb32 + (size_t)row2 * 128 + cc] = hv;
          }
        } else if (u == 3) {
          // MFMA burst: z_{tb+4+rr} = sigmoid(xz + h_{tb-1+rr} @ Uz)
          const int sIdx = (tb + 7 + (l & 3)) & 7;   // rows m>=4 duplicate 0..3 (discarded)
          const int lo4 = (l >> 4) * 4;
          float4v acc[4] = {};
#pragma unroll
          for (int kt = 0; kt < 8; ++kt) {
            half8v a = __builtin_bit_cast(half8v, *(const uint4*)&histS[sIdx][kt * 16 + lo4]);
#pragma unroll
            for (int nt = 0; nt < 4; ++nt)
              acc[nt] = __builtin_amdgcn_mfma_f32_16x16x32_f16(
                  a, __builtin_bit_cast(half8v, W[kt * 4 + nt]), acc[nt], 0, 0, 0);
          }
          if (l < 16) {
#pragma unroll
            for (int nt = 0; nt < 4; ++nt)
#pragma unroll
              for (int rr2 = 0; rr2 < 4; ++rr2) {
                float zv = sigmoid_f(acc[nt][rr2] + h16tof(xq[nt][rr2]));
                zringS[(tb + 4 + rr2) & 7][wv * 64 + nt * 16 + l] = ftoh16(zv);
              }
          }
        }
        // u==1, u==2: idle (barrier only)
      }
      __syncthreads();
    }
  }

  // tail: write back h rows 4092..4095
  if (g == 1) {
    const int idx = (w - 4) * 64 + l;
    const int rr = idx >> 6, cc = (idx & 63) * 2;
    const int row = 4092 + rr;
    uint2 hv = *(const uint2*)&histS[row & 7][cc];
    *(uint2*)&hsOut[xb32 + (size_t)row * 128 + cc] = hv;
  }
}

// ---------------------------------------------------------------------------
extern "C" void kernel_launch(void* const* d_in, const int* in_sizes, int n_in,
                              void* d_out, int out_size, void* d_ws, size_t ws_size,
                              hipStream_t stream)
{
  (void)in_sizes; (void)n_in; (void)out_size; (void)ws_size;
  const float* x  = (const float*)d_in[0];
  const float* Wz = (const float*)d_in[1];
  const float* Uz = (const float*)d_in[2];
  const float* bz = (const float*)d_in[3];
  const float* Wh = (const float*)d_in[4];
  const float* Uh = (const float*)d_in[5];
  const float* bh = (const float*)d_in[6];
  const float* Wo = (const float*)d_in[7];
  const float* bo = (const float*)d_in[8];

  char* ws = (char*)d_ws;
  _Float16* Wzt  = (_Float16*)(ws);                                   // 64 KB
  _Float16* Wht  = (_Float16*)(ws + (64 << 10));                      // 64 KB
  _Float16* Wot  = (_Float16*)(ws + (128 << 10));                     // 64 KB
  _Float16* xz16 = (_Float16*)(ws + (256 << 10));                     // 64 MB
  _Float16* xh16 = (_Float16*)(ws + (256 << 10) + (size_t)64 * 1024 * 1024); // 64 MB

  _Float16* hs16 = (_Float16*)d_out;  // hs staged in d_out; head GEMM in-place

  prep_transpose<<<dim3(32, 3), 256, 0, stream>>>(Wz, Wh, Wo, Wzt, Wht, Wot);
  gemm_mfma<128, 256, true, true><<<1024, 256, 0, stream>>>(x, Wzt, bz, xz16);
  gemm_mfma<128, 256, true, true><<<1024, 256, 0, stream>>>(x, Wht, bh, xh16);
  scan_kernel<<<32, 512, 0, stream>>>((const u32*)xz16, (const u32*)xh16,
                                      Uz, Uh, (u32*)d_out);
  gemm_mfma<256, 128, false, false><<<1024, 256, 0, stream>>>(hs16, Wot, bo, d_out);
}

// Round 3
// 3622.350 us; speedup vs baseline: 1.2029x; 1.0704x over previous
//
#include <hip/hip_runtime.h>
#include <hip/hip_bf16.h>

typedef _Float16 half2v __attribute__((ext_vector_type(2)));
typedef _Float16 half8v __attribute__((ext_vector_type(8)));
typedef float float4v __attribute__((ext_vector_type(4)));
typedef unsigned int u32;
typedef unsigned short u16;

#define DEV static __device__ __forceinline__

DEV u32 pack2(float a, float b) {
  half2v h = { (_Float16)a, (_Float16)b };
  return __builtin_bit_cast(u32, h);
}
DEV half2v uph(u32 u) { return __builtin_bit_cast(half2v, u); }
DEV u16 ftoh16(float f) { return __builtin_bit_cast(u16, (_Float16)f); }
DEV float h16tof(u16 s) { return (float)__builtin_bit_cast(_Float16, s); }

#if __has_builtin(__builtin_amdgcn_fdot2)
DEV float fdot2(half2v a, half2v b, float c) { return __builtin_amdgcn_fdot2(a, b, c, false); }
#else
DEV float fdot2(half2v a, half2v b, float c) {
  return c + (float)a.x * (float)b.x + (float)a.y * (float)b.y;
}
#endif

DEV float fast_rcp(float x) { return __builtin_amdgcn_rcpf(x); }
DEV float sigmoid_f(float x) { return fast_rcp(1.f + exp2f(-1.4426950408889634f * x)); }
DEV float tanh_f(float x) {
  float e = exp2f(x * 2.8853900817779268f);  // e^(2x)
  return 1.f - 2.f * fast_rcp(e + 1.f);
}

// Raw barrier: LDS-publish only. Deliberately NO vmcnt(0) — in-flight global
// loads/stores keep flying across it (the compiler's own data-dep vmcnt(N)
// drains them right before their LDS write, 3 steps after issue).
DEV void barrier_lgkm() {
  __asm__ __volatile__("s_waitcnt lgkmcnt(0)\ns_barrier" ::: "memory");
}

// ---------------------------------------------------------------------------
// Prep: transpose + f16-convert the three weight matrices (dst[c][r] = src[r][c])
// ---------------------------------------------------------------------------
__global__ void prep_transpose(const float* __restrict__ Wz, const float* __restrict__ Wh,
                               const float* __restrict__ Wo, _Float16* __restrict__ Wzt,
                               _Float16* __restrict__ Wht, _Float16* __restrict__ Wot)
{
  const float* src; _Float16* dst; int R, C;
  if (blockIdx.y == 0)      { src = Wz; dst = Wzt; R = 128; C = 256; }
  else if (blockIdx.y == 1) { src = Wh; dst = Wht; R = 128; C = 256; }
  else                      { src = Wo; dst = Wot; R = 256; C = 128; }
  int total = R * C;
  for (int idx = blockIdx.x * blockDim.x + threadIdx.x; idx < total;
       idx += gridDim.x * blockDim.x) {
    int rr = idx / C, cc = idx % C;
    dst[(size_t)cc * R + rr] = (_Float16)src[idx];
  }
}

// ---------------------------------------------------------------------------
// MFMA GEMM: out[M x N] = A[M x K] * Bt^T (+bias). Bt is [N][K] f16 (pre-transposed).
// ---------------------------------------------------------------------------
template <int K, int N, bool A_F32, bool OUT_F16>
__global__ __launch_bounds__(256, 2) void gemm_mfma(
    const void* __restrict__ A_, const _Float16* __restrict__ Bt,
    const float* __restrict__ bias, void* __restrict__ out)
{
  __shared__ _Float16 Blds[N * K];  // 64 KB

  const int tid = threadIdx.x;
  constexpr int CHUNKS = K / 8;
  constexpr int ITER = (N * K / 8) / 256;
#pragma unroll
  for (int i = 0; i < ITER; ++i) {
    int idx = tid + i * 256;
    int n = idx / CHUNKS;
    int c = idx % CHUNKS;
    int cs = c ^ (n & 7);
    *(uint4*)(Blds + (size_t)n * K + cs * 8) =
        *(const uint4*)(Bt + (size_t)n * K + c * 8);
  }
  __syncthreads();

  const int w = tid >> 6, l = tid & 63;
  const int lm = l & 15, lq = l >> 4;
  const size_t m0 = (size_t)blockIdx.x * 128;

  float4v acc[2][N / 16] = {};

#pragma unroll
  for (int kk = 0; kk < K / 32; ++kk) {
    const int kbase = kk * 32 + lq * 8;
    half8v af[2];
#pragma unroll
    for (int ms = 0; ms < 2; ++ms) {
      const size_t row = m0 + (size_t)(w * 2 + ms) * 16 + lm;
      if constexpr (A_F32) {
        const float* ap = (const float*)A_ + row * K + kbase;
        float4 x0 = *(const float4*)ap;
        float4 x1 = *(const float4*)(ap + 4);
        af[ms] = half8v{(_Float16)x0.x, (_Float16)x0.y, (_Float16)x0.z, (_Float16)x0.w,
                        (_Float16)x1.x, (_Float16)x1.y, (_Float16)x1.z, (_Float16)x1.w};
      } else {
        af[ms] = *(const half8v*)((const _Float16*)A_ + row * K + kbase);
      }
    }
    const int c = kk * 4 + lq;
#pragma unroll
    for (int nt = 0; nt < N / 16; ++nt) {
      const int n = nt * 16 + lm;
      half8v bf = *(const half8v*)(Blds + (size_t)n * K + (c ^ (lm & 7)) * 8);
      acc[0][nt] = __builtin_amdgcn_mfma_f32_16x16x32_f16(af[0], bf, acc[0][nt], 0, 0, 0);
      acc[1][nt] = __builtin_amdgcn_mfma_f32_16x16x32_f16(af[1], bf, acc[1][nt], 0, 0, 0);
    }
  }

#pragma unroll
  for (int ms = 0; ms < 2; ++ms) {
    const size_t rowbase = m0 + (size_t)(w * 2 + ms) * 16 + lq * 4;
#pragma unroll
    for (int nt = 0; nt < N / 16; ++nt) {
      const int col = nt * 16 + lm;
      const float bcol = bias[col];
#pragma unroll
      for (int rr = 0; rr < 4; ++rr) {
        const size_t row = rowbase + rr;
        float v = acc[ms][nt][rr] + bcol;
        if constexpr (OUT_F16) ((_Float16*)out)[row * N + col] = (_Float16)v;
        else                   ((float*)out)[row * N + col] = v;
      }
    }
  }
}

// ---------------------------------------------------------------------------
// Sequential scan. One WG (512 thr, 8 waves) per batch element.
//  g0 (waves 0-3): candidate gate. 1 column/lane, full K=256 per lane.
//    a-vector = zh ring (z_t (.) h_{t-1}, precomputed) -> inner loop is
//    32 broadcast ds_read_b128 + 128 fdot2, ZERO bank conflicts, no shfl.
//  g1 (waves 4-7): z gate via MFMA once per 4 steps (u==3); all global
//    traffic issued at u==0 into REGISTERS, ds_written to LDS at u==3 so the
//    vmcnt wait lands ~3 steps (~1600cy) after issue. Raw lgkm-only barriers
//    keep HBM latency off the barrier path entirely.
//  Barriers: 5 per 4-step group (B0..B3 + mini-barrier B4 that publishes the
//  group-boundary zh after g1's z burst lands).
// ---------------------------------------------------------------------------
__global__ __launch_bounds__(512, 2) void scan_kernel(
    const u32* __restrict__ xz32, const u32* __restrict__ xh32,
    const float* __restrict__ Uz, const float* __restrict__ Uh,
    u32* __restrict__ hsOut)
{
  const int b   = blockIdx.x;
  const int tid = threadIdx.x;
  const int w   = tid >> 6;
  const int l   = tid & 63;
  const int g   = w >> 2;
  const int wv  = w & 3;

  // pitch 264 u16 (=528B): ring slots are 4 banks apart -> the 4-row MFMA
  // A-frag reads hit disjoint bank quads.
  __shared__ __align__(16) u16 histS[8][264];   // h_t, f16, 1 col per u16
  __shared__ __align__(16) u16 zringS[8][264];  // z_t
  __shared__ __align__(16) u16 zhS[8][264];     // z_t * h_{t-1}  (a-vector)
  __shared__ __align__(16) u16 xhS[2][1024];    // xh staging, 4 rows x 256
  __shared__ __align__(16) u16 xzS[2][1024];    // xz staging, 4 rows x 256

  uint4 W[32];  // overlay: g0 = Uh column c packs; g1 = Uz B-frags

  const size_t xb32 = (size_t)b * 4096 * 128;   // u32 units
  const u16* xz16v = (const u16*)xz32;
  const int c   = wv * 64 + l;        // g0: owned column / g1: linear id
  const int rr  = c >> 6;             // staging row 0..3
  const int c4  = (c & 63) * 4;       // staging col (u16), 4 per thread

  if (g == 0) {
    // Uh column c -> 128 packed f16 row-pairs (coalesced across lanes)
    const float* Ub = Uh + c;
#pragma unroll
    for (int i = 0; i < 32; ++i) {
      u32 q[4];
#pragma unroll
      for (int p2 = 0; p2 < 4; ++p2) {
        int k0 = i * 8 + p2 * 2;
        q[p2] = pack2(Ub[(size_t)k0 * 256], Ub[(size_t)(k0 + 1) * 256]);
      }
      W[i] = make_uint4(q[0], q[1], q[2], q[3]);
    }
  } else {
    // Uz -> B-fragments: W[kt*4+nt], B[k=kt*32+(l>>4)*8+j][n=wv*64+nt*16+(l&15)]
    const int lm = l & 15, lo = (l >> 4) * 8;
#pragma unroll
    for (int kt = 0; kt < 8; ++kt)
#pragma unroll
      for (int nt = 0; nt < 4; ++nt) {
        u32 q[4];
#pragma unroll
        for (int p2 = 0; p2 < 4; ++p2) {
          int k0 = kt * 32 + lo + 2 * p2;
          int cn = wv * 64 + nt * 16 + lm;
          q[p2] = pack2(Uz[(size_t)k0 * 256 + cn], Uz[(size_t)(k0 + 1) * 256 + cn]);
        }
        W[kt * 4 + nt] = make_uint4(q[0], q[1], q[2], q[3]);
      }
  }

  // zero h_{-4..-1} (slots 4..7) and zh_0 (= z_0 * h_{-1} = 0)
  for (int i = tid; i < 4 * 264; i += 512) (&histS[4][0])[i] = 0;
  for (int i = tid; i < 264; i += 512) zhS[0][i] = 0;

  if (g == 1) {
    // z_0..3 = sigmoid(xz rows 0..3);  stage xh rows 0..3, xz rows 4..7
    uint2 xzv = *(const uint2*)&xz16v[((size_t)b * 4096 + rr) * 256 + c4];
    half2v a0 = uph(xzv.x), a1 = uph(xzv.y);
    u32 z01 = pack2(sigmoid_f((float)a0.x), sigmoid_f((float)a0.y));
    u32 z23 = pack2(sigmoid_f((float)a1.x), sigmoid_f((float)a1.y));
    *(uint2*)&zringS[rr][c4] = make_uint2(z01, z23);
    *(uint2*)&xhS[0][rr * 256 + c4] =
        *(const uint2*)&xh32[xb32 + (size_t)rr * 128 + (c & 63) * 2];
    *(uint2*)&xzS[0][rr * 256 + c4] =
        *(const uint2*)&xz16v[((size_t)b * 4096 + 4 + rr) * 256 + c4];
  }
  float h = 0.f;
  __syncthreads();

  for (int tb = 0; tb < 4096; tb += 4) {
    const int p = (tb >> 2) & 1;
    uint2 xhv, xzv2;                      // g1: staged in regs u0 -> u3
#pragma unroll
    for (int u = 0; u < 4; ++u) {
      const int t = tb + u;
      if (g == 0) {
        // ---------------- candidate gate: h_t (column c) ----------------
        const uint4* a4 = (const uint4*)&zhS[t & 7][0];   // broadcast reads
        float xh_t = h16tof(xhS[p][u * 256 + c]);
        float z_t  = h16tof(zringS[t & 7][c]);
        float s0 = 0.f, s1 = 0.f, s2 = 0.f, s3 = 0.f;
#pragma unroll
        for (int i = 0; i < 32; ++i) {
          uint4 A = a4[i];
          uint4 Wq = W[i];
          s0 = fdot2(uph(A.x), uph(Wq.x), s0);
          s1 = fdot2(uph(A.y), uph(Wq.y), s1);
          s2 = fdot2(uph(A.z), uph(Wq.z), s2);
          s3 = fdot2(uph(A.w), uph(Wq.w), s3);
        }
        float acc = (s0 + s1) + (s2 + s3);
        float htl = tanh_f(acc + xh_t);
        h += z_t * (htl - h);
        histS[t & 7][c] = ftoh16(h);
        if (u < 3) {                      // z_{t+1} already published
          float zn = h16tof(zringS[(t + 1) & 7][c]);
          zhS[(t + 1) & 7][c] = ftoh16(zn * h);
        }
        barrier_lgkm();                   // B_u
        if (u == 3) {                     // B3 published z_{tb+4}; finish zh
          float zn = h16tof(zringS[(t + 1) & 7][c]);
          zhS[(t + 1) & 7][c] = ftoh16(zn * h);
          barrier_lgkm();                 // B4
        }
      } else {
        // ---------------- z gate + all global traffic ----------------
        if (u == 0) {
          int rh = tb + 4 + rr; if (rh > 4095) rh = 4095;
          xhv = *(const uint2*)&xh32[xb32 + (size_t)rh * 128 + (c & 63) * 2];
          int rz = tb + 8 + rr; if (rz > 4095) rz = 4095;
          xzv2 = *(const uint2*)&xz16v[((size_t)b * 4096 + rz) * 256 + c4];
          if (tb > 0) {                   // write back h rows tb-4..tb-1
            int ro = tb - 4 + rr;
            uint2 hv = *(const uint2*)&histS[ro & 7][c4];
            *(uint2*)&hsOut[xb32 + (size_t)ro * 128 + (c & 63) * 2] = hv;
          }
          barrier_lgkm();
        } else if (u == 3) {
          // publish staged xh/xz (vmcnt(N) wait lands here, ~3 steps late)
          *(uint2*)&xhS[p ^ 1][rr * 256 + c4] = xhv;
          *(uint2*)&xzS[p ^ 1][rr * 256 + c4] = xzv2;
          // MFMA burst: z_{tb+4+r2} = sigmoid(xz + h_{tb-1+r2} @ Uz)
          const int srow = (tb + 7 + (l & 3)) & 7;   // m%4 row select
          const int koff = (l >> 4) * 8;
          float4v acc4[4] = {};
#pragma unroll
          for (int kt = 0; kt < 8; ++kt) {
            half8v a = __builtin_bit_cast(
                half8v, *(const uint4*)&histS[srow][kt * 32 + koff]);
#pragma unroll
            for (int nt = 0; nt < 4; ++nt)
              acc4[nt] = __builtin_amdgcn_mfma_f32_16x16x32_f16(
                  a, __builtin_bit_cast(half8v, W[kt * 4 + nt]), acc4[nt], 0, 0, 0);
          }
          if (l < 16) {                    // C: lanes 0-15 hold m=reg rows
#pragma unroll
            for (int nt = 0; nt < 4; ++nt) {
              int cn = wv * 64 + nt * 16 + l;
#pragma unroll
              for (int r2 = 0; r2 < 4; ++r2) {
                float zv = sigmoid_f(acc4[nt][r2] + h16tof(xzS[p][r2 * 256 + cn]));
                zringS[(tb + 4 + r2) & 7][cn] = ftoh16(zv);
              }
            }
          }
          barrier_lgkm();                 // B3
          barrier_lgkm();                 // B4
        } else {
          barrier_lgkm();                 // B1 / B2
        }
      }
    }
  }

  // tail: write back h rows 4092..4095
  if (g == 1) {
    int ro = 4092 + rr;
    uint2 hv = *(const uint2*)&histS[ro & 7][c4];
    *(uint2*)&hsOut[xb32 + (size_t)ro * 128 + (c & 63) * 2] = hv;
  }
}

// ---------------------------------------------------------------------------
extern "C" void kernel_launch(void* const* d_in, const int* in_sizes, int n_in,
                              void* d_out, int out_size, void* d_ws, size_t ws_size,
                              hipStream_t stream)
{
  (void)in_sizes; (void)n_in; (void)out_size; (void)ws_size;
  const float* x  = (const float*)d_in[0];
  const float* Wz = (const float*)d_in[1];
  const float* Uz = (const float*)d_in[2];
  const float* bz = (const float*)d_in[3];
  const float* Wh = (const float*)d_in[4];
  const float* Uh = (const float*)d_in[5];
  const float* bh = (const float*)d_in[6];
  const float* Wo = (const float*)d_in[7];
  const float* bo = (const float*)d_in[8];

  char* ws = (char*)d_ws;
  _Float16* Wzt  = (_Float16*)(ws);                                   // 64 KB
  _Float16* Wht  = (_Float16*)(ws + (64 << 10));                      // 64 KB
  _Float16* Wot  = (_Float16*)(ws + (128 << 10));                     // 64 KB
  _Float16* xz16 = (_Float16*)(ws + (256 << 10));                     // 64 MB
  _Float16* xh16 = (_Float16*)(ws + (256 << 10) + (size_t)64 * 1024 * 1024); // 64 MB

  _Float16* hs16 = (_Float16*)d_out;  // hs staged in d_out; head GEMM in-place

  prep_transpose<<<dim3(32, 3), 256, 0, stream>>>(Wz, Wh, Wo, Wzt, Wht, Wot);
  gemm_mfma<128, 256, true, true><<<1024, 256, 0, stream>>>(x, Wzt, bz, xz16);
  gemm_mfma<128, 256, true, true><<<1024, 256, 0, stream>>>(x, Wht, bh, xh16);
  scan_kernel<<<32, 512, 0, stream>>>((const u32*)xz16, (const u32*)xh16,
                                      Uz, Uh, (u32*)d_out);
  gemm_mfma<256, 128, false, false><<<1024, 256, 0, stream>>>(hs16, Wot, bo, d_out);
}